// Round 8
// baseline (545.497 us; speedup 1.0000x reference)
//
#include <hip/hip_runtime.h>

typedef _Float16 f16x8 __attribute__((ext_vector_type(8)));
typedef _Float16 f16x4 __attribute__((ext_vector_type(4)));
typedef float    f32x4 __attribute__((ext_vector_type(4)));

#define MFMA(a,b,c) __builtin_amdgcn_mfma_f32_16x16x32_f16((a),(b),(c),0,0,0)

// ws layout (bytes): [0)      M~  f16 [128][128]  (scale * Wk^T Wq)
//                    [32768)  Wv' f16 [128][128]  (Wo @ Wv)
//                    [65536)  biases f32: t[128] = scale*Wk^T bq, b'[128] = Wo bv + bo
// Algebra: softmax over key-axis i is invariant to per-j offsets, so
//   S[i][j] = x_i^T (M x_j + t)  with M = scale*Wk^T Wq, t = scale*Wk^T bq
// (bk-only and constant terms drop). out = Wv' (X A) + b' + x.
//
// Design rules established R0-R7 (hard-won):
//  - NON-persistent, phase-aligned dispatch (cross-block persistence desyncs
//    sibling stores -> partial-line RMW: R3/R6 +150-290MB each way).
//  - Store granule >=32B; the two 32B halves of each 64B line must come from
//    the SAME block (this kernel: two sequential 8-w halves) or lockstep
//    siblings. R7 proved read- and write-traffic hit ideal; R8 attacks the
//    exposed latency (1 blk/CU, serialized phases, 4 ramp rounds).

// ---------------- prep: fold weights ----------------
__global__ __launch_bounds__(128) void prep_kernel(
    const float* __restrict__ Wk, const float* __restrict__ bk,
    const float* __restrict__ Wq, const float* __restrict__ bq,
    const float* __restrict__ Wv, const float* __restrict__ bv,
    const float* __restrict__ Wo, const float* __restrict__ bo,
    _Float16* __restrict__ wh, float* __restrict__ bf) {
  __shared__ float shK[128], shO[128];
  const int o = blockIdx.x;
  const int c = threadIdx.x;
  const float scale = 0.08838834764831844f;  // 1/sqrt(128)
  shK[c] = Wk[c*128 + o];      // Wk[m][o]  (column o)
  shO[c] = Wo[o*128 + c];      // Wo[o][m]
  __syncthreads();
  float aM = 0.f, aV = 0.f, tK = 0.f, bV = 0.f;
  for (int m = 0; m < 128; ++m) {
    aM += shK[m] * Wq[m*128 + c];   // M[o][c]
    aV += shO[m] * Wv[m*128 + c];   // Wv'[o][c]
    tK += shK[m] * bq[m];
    bV += shO[m] * bv[m];
  }
  wh[o*128 + c]         = (_Float16)(aM * scale);
  wh[16384 + o*128 + c] = (_Float16)aV;
  if (c == 0) { bf[o] = tK * scale; bf[128 + o] = bV + bo[o]; }
}

__device__ __forceinline__ f16x4 cvt4(f32x4 v, f32x4 b) {
  f16x4 r;
  r[0] = (_Float16)(v[0] + b[0]); r[1] = (_Float16)(v[1] + b[1]);
  r[2] = (_Float16)(v[2] + b[2]); r[3] = (_Float16)(v[3] + b[3]);
  return r;
}
__device__ __forceinline__ f16x4 cvt4z(f32x4 v) {
  f16x4 r;
  r[0] = (_Float16)v[0]; r[1] = (_Float16)v[1];
  r[2] = (_Float16)v[2]; r[3] = (_Float16)v[3];
  return r;
}

// XOR swizzle for Xt/Yt [256 rows][128 f16 cols], 256B rows, no padding.
// XOR folds row, row>>3 (stride-8-row accesses) and row>>5 (stride-64) so
// all phase patterns land >=8 distinct 16B chunks per 16 lanes. The XOR only
// permutes 16B chunks (byte bits 4..6), so 8B-aligned sub-writes stay intact.
__device__ __forceinline__ int xsw(int row, int col /*f16 units*/) {
  return ((row << 8) | (col << 1)) ^ (((row ^ (row >> 3) ^ (row >> 5)) & 7) << 4);
}

// ---- one 8-w half: P2(Y) -> P3(S+softmax) -> P5(U) -> P6(out) ----
// Expects Xt already populated for this half; enters with a barrier.
__device__ __forceinline__ void half_pass(
    char* XtB, char* YtB, _Float16* At,
    const _Float16* __restrict__ wh, const float* __restrict__ bfp,
    float* __restrict__ out, size_t pbaseh,
    int wv, int quad, int l15, const f16x8 (&wm)[4], f32x4 t4, float bb) {
  const f32x4 zz = {0.f, 0.f, 0.f, 0.f};
  const int mi = wv & 7, ni = wv >> 3;
  __syncthreads();   // Xt ready

  // ---- P2: Y = M~ X + t  -> Yt (rows = voxel d*8+p, cols = c1) ----
  {
    f32x4 aY[8] = {zz, zz, zz, zz, zz, zz, zz, zz};
#pragma unroll
    for (int kk = 0; kk < 4; ++kk) {
      const int co = kk*32 + quad*8;
#pragma unroll
      for (int nt = 0; nt < 8; ++nt) {
        const f16x8 bfv = *(const f16x8*)(XtB + xsw(ni*128 + nt*16 + l15, co));
        aY[nt] = MFMA(wm[kk], bfv, aY[nt]);
      }
    }
#pragma unroll
    for (int nt = 0; nt < 8; ++nt)
      *(f16x4*)(YtB + xsw(ni*128 + nt*16 + l15, mi*16 + quad*4)) = cvt4(aY[nt], t4);
  }
  __syncthreads();

  // ---- P3: S = X^T Y per pixel; wave = (pixel p, j-half tj); softmax -> At ----
  {
    const int p = wv & 7, tj = wv >> 3;
    f32x4 aS[2] = {zz, zz};
#pragma unroll
    for (int kk = 0; kk < 4; ++kk) {
      const int co = kk*32 + quad*8;
      const f16x8 by = *(const f16x8*)(YtB + xsw((tj*16 + l15)*8 + p, co));
#pragma unroll
      for (int ti = 0; ti < 2; ++ti) {
        const f16x8 ak = *(const f16x8*)(XtB + xsw((ti*16 + l15)*8 + p, co));
        aS[ti] = MFMA(ak, by, aS[ti]);
      }
    }
    // lane holds S[i = ti*16+quad*4+r][j = tj*16+l15]; reduce over i
    float mx = aS[0][0];
#pragma unroll
    for (int r = 1; r < 4; ++r) mx = fmaxf(mx, aS[0][r]);
#pragma unroll
    for (int r = 0; r < 4; ++r) mx = fmaxf(mx, aS[1][r]);
    mx = fmaxf(mx, __shfl_xor(mx, 16));
    mx = fmaxf(mx, __shfl_xor(mx, 32));
    float e[2][4];
    float den = 0.f;
#pragma unroll
    for (int ti = 0; ti < 2; ++ti)
#pragma unroll
      for (int r = 0; r < 4; ++r) { e[ti][r] = __expf(aS[ti][r] - mx); den += e[ti][r]; }
    den += __shfl_xor(den, 16);
    den += __shfl_xor(den, 32);
    const float rr = 1.0f / den;
#pragma unroll
    for (int ti = 0; ti < 2; ++ti) {
      f16x4 av;
#pragma unroll
      for (int r = 0; r < 4; ++r) av[r] = (_Float16)(e[ti][r] * rr);
      *(f16x4*)(At + (p*32 + tj*16 + l15)*40 + ti*16 + quad*4) = av;
    }
  }
  __syncthreads();

  // ---- P5: U = X A per pixel -> Yt (U^T rows = j*8+p); load Wv' frags ----
  f16x8 wp[4];
  {
#pragma unroll
    for (int kk = 0; kk < 4; ++kk)
      wp[kk] = *(const f16x8*)(wh + 16384 + (mi*16 + l15)*128 + kk*32 + quad*8);
    const int p = wv & 7, mg = wv >> 3;
    f16x8 bA[2];
#pragma unroll
    for (int tj = 0; tj < 2; ++tj)
      bA[tj] = *(const f16x8*)(At + (p*32 + tj*16 + l15)*40 + quad*8);
#pragma unroll
    for (int t2 = 0; t2 < 4; ++t2) {
      const int ms = mg*4 + t2;
      f16x8 ax;
#pragma unroll
      for (int jj = 0; jj < 8; ++jj)
        ax[jj] = *(const _Float16*)(XtB + xsw((quad*8 + jj)*8 + p, ms*16 + l15));
#pragma unroll
      for (int tj = 0; tj < 2; ++tj) {
        const f32x4 aU = MFMA(ax, bA[tj], zz);
        *(f16x4*)(YtB + xsw((tj*16 + l15)*8 + p, ms*16 + quad*4)) = cvt4z(aU);
      }
    }
  }
  __syncthreads();

  // ---- P6: out^T = U^T Wv'^T + b' + x : 32B stores (line completed by the
  // other half of this same block -> merge is timing-proof) ----
  {
    const int oi = wv & 7, mg6 = wv >> 3;
    f32x4 acc[8] = {zz, zz, zz, zz, zz, zz, zz, zz};
#pragma unroll
    for (int kk = 0; kk < 4; ++kk) {
      const int co = kk*32 + quad*8;
#pragma unroll
      for (int mt = 0; mt < 8; ++mt) {
        const f16x8 av = *(const f16x8*)(YtB + xsw((mg6*8 + mt)*16 + l15, co));
        acc[mt] = MFMA(av, wp[kk], acc[mt]);
      }
    }
    const int o = oi*16 + l15;
    float* outp = out + pbaseh + (size_t)o*131072;
#pragma unroll
    for (int mt = 0; mt < 8; ++mt) {
      const int vox0 = (mg6*8 + mt)*16 + quad*4;   // voxel = d*8 + p
      const int d = vox0 >> 3;
      f32x4 vv;
#pragma unroll
      for (int r = 0; r < 4; ++r)
        vv[r] = acc[mt][r] + bb +
                (float)*(const _Float16*)(XtB + xsw(vox0 + r, o));
      *(f32x4*)(outp + (size_t)d*4096 + (vox0 & 7)) = vv;
    }
  }
  __syncthreads();   // Xt/Yt free for the next half's transpose
}

// ---------------- fused attention (N=16 block as two 8-w halves) ----------------
// grid = 512 blocks x 1024 thr; block owns 16 consecutive w = full 64B x-lines
// and out-lines. Half A: w+0..7; half B: w+8..15. B's x loads issue right
// after A's transpose (A's fetches primed the 64B lines -> B hits L2/L3, fully
// hidden under A's compute); A's HBM writeback drains under B's compute
// (barrier only waits store-ack-to-L2). Rounds: 4 -> 2. LDS 148KB, 1 blk/CU.
__global__ __launch_bounds__(1024, 4) void attn_kernel(
    const float* __restrict__ x, const _Float16* __restrict__ wh,
    const float* __restrict__ bfp, float* __restrict__ out) {
  __shared__ __align__(16) char lds[151552];
  char* XtB = lds;                      // [256 r=d*8+p][128 c] f16, swizzled (64KB)
  char* YtB = lds + 65536;              // Y^T, later U^T, swizzled (64KB)
  _Float16* At = (_Float16*)(lds + 131072);  // [p*32+j][40 i] f16 (20KB)

  const int tid  = threadIdx.x;
  const int lane = tid & 63;
  const int wv   = tid >> 6;            // 0..15
  const int quad = lane >> 4;
  const int l15  = lane & 15;

  const int bid = blockIdx.x;           // 0..511
  const int b   = bid >> 8;
  const int rem = bid & 255;
  const int h   = rem >> 2;
  const int w16 = rem & 3;
  const size_t pbase = (size_t)b * 16777216u + (size_t)(h*64 + w16*16);

  // ---- half-A x loads issued FIRST (longest latency) ----
  const int c4 = tid & 31;              // c-quad 0..31
  const int dd = tid >> 5;              // d 0..31
  const float* xg = x + pbase + (size_t)c4*4*131072 + (size_t)dd*4096;
  f32x4 vA[4][2];
#pragma unroll
  for (int r = 0; r < 4; ++r)
#pragma unroll
    for (int i = 0; i < 2; ++i)
      vA[r][i] = *(const f32x4*)(xg + (size_t)r*131072 + i*4);

  // ---- resident weight fragments + biases (overlap with x loads) ----
  const int mi = wv & 7;
  f16x8 wm[4];
#pragma unroll
  for (int kk = 0; kk < 4; ++kk)
    wm[kk] = *(const f16x8*)(wh + (mi*16 + l15)*128 + kk*32 + quad*8);
  const f32x4 t4 = *(const f32x4*)(bfp + mi*16 + quad*4);
  const float bb = bfp[128 + (wv & 7)*16 + l15];   // P6 bias (oi = wv&7)

  // ---- transpose A -> Xt (swizzled), 8 x ds_write_b64 ----
#pragma unroll
  for (int i = 0; i < 2; ++i)
#pragma unroll
    for (int p = 0; p < 4; ++p) {
      f16x4 t;
#pragma unroll
      for (int r = 0; r < 4; ++r) t[r] = (_Float16)vA[r][i][p];
      *(f16x4*)(XtB + xsw(dd*8 + i*4 + p, c4*4)) = t;
    }

  // ---- issue half-B x loads now (lines L2-primed by A; hidden under pass A) ----
  f32x4 vB[4][2];
#pragma unroll
  for (int r = 0; r < 4; ++r)
#pragma unroll
    for (int i = 0; i < 2; ++i)
      vB[r][i] = *(const f32x4*)(xg + (size_t)r*131072 + 8 + i*4);

  // ---- pass A (w+0..7) ----
  half_pass(XtB, YtB, At, wh, bfp, out, pbase, wv, quad, l15, wm, t4, bb);

  // ---- transpose B -> Xt ----
#pragma unroll
  for (int i = 0; i < 2; ++i)
#pragma unroll
    for (int p = 0; p < 4; ++p) {
      f16x4 t;
#pragma unroll
      for (int r = 0; r < 4; ++r) t[r] = (_Float16)vB[r][i][p];
      *(f16x4*)(XtB + xsw(dd*8 + i*4 + p, c4*4)) = t;
    }

  // ---- pass B (w+8..15) ----
  half_pass(XtB, YtB, At, wh, bfp, out, pbase + 8, wv, quad, l15, wm, t4, bb);
}

extern "C" void kernel_launch(void* const* d_in, const int* in_sizes, int n_in,
                              void* d_out, int out_size, void* d_ws, size_t ws_size,
                              hipStream_t stream) {
  const float* x  = (const float*)d_in[0];
  const float* Wk = (const float*)d_in[1];
  const float* bk = (const float*)d_in[2];
  const float* Wq = (const float*)d_in[3];
  const float* bq = (const float*)d_in[4];
  const float* Wv = (const float*)d_in[5];
  const float* bv = (const float*)d_in[6];
  const float* Wo = (const float*)d_in[7];
  const float* bo = (const float*)d_in[8];
  float* out = (float*)d_out;
  _Float16* wh = (_Float16*)d_ws;
  float* bf = (float*)((char*)d_ws + 65536);

  prep_kernel<<<dim3(128), dim3(128), 0, stream>>>(Wk, bk, Wq, bq, Wv, bv, Wo, bo, wh, bf);
  attn_kernel<<<dim3(512), dim3(1024), 0, stream>>>(x, wh, bf, out);
}

// Round 9
// 537.548 us; speedup vs baseline: 1.0148x; 1.0148x over previous
//
#include <hip/hip_runtime.h>

typedef _Float16 f16x8 __attribute__((ext_vector_type(8)));
typedef _Float16 f16x4 __attribute__((ext_vector_type(4)));
typedef float    f32x4 __attribute__((ext_vector_type(4)));

#define MFMA(a,b,c) __builtin_amdgcn_mfma_f32_16x16x32_f16((a),(b),(c),0,0,0)

// ws layout (bytes): [0)      M~  f16 [128][128]  (scale * Wk^T Wq)
//                    [32768)  Wv' f16 [128][128]  (Wo @ Wv)
//                    [65536)  biases f32: t[128] = scale*Wk^T bq, b'[128] = Wo bv + bo
// Algebra: softmax over key-axis i is invariant to per-j offsets, so
//   S[i][j] = x_i^T (M x_j + t)  with M = scale*Wk^T Wq, t = scale*Wk^T bq
// (bk-only and constant terms drop). out = Wv' (X A) + b' + x.
//
// Design rules established R0-R8 (hard-won):
//  - Partial 64B out-lines merge in L2 ONLY when both 32B halves are written
//    at the same phase time of the same dispatch round (lockstep siblings).
//    R5 (sibling blocks, same pass): WRITE 143MB = clean. R6/R8 (halves
//    ~20-100us apart): RMW, +134MB fetch +134MB write. So: halves pair
//    ACROSS SIBLING BLOCKS (bid, bid+8) WITHIN each pass, never across passes.
//  - NON-persistent, phase-aligned dispatch; fresh blocks are the clock.
//  - Two sequential passes per block are fine for everything EXCEPT line
//    pairing: they halve ramp count and let pass-B loads prefetch under
//    pass-A compute (R8 verified: VGPR stays 64, B loads hit L2).

// ---------------- prep: fold weights ----------------
__global__ __launch_bounds__(128) void prep_kernel(
    const float* __restrict__ Wk, const float* __restrict__ bk,
    const float* __restrict__ Wq, const float* __restrict__ bq,
    const float* __restrict__ Wv, const float* __restrict__ bv,
    const float* __restrict__ Wo, const float* __restrict__ bo,
    _Float16* __restrict__ wh, float* __restrict__ bf) {
  __shared__ float shK[128], shO[128];
  const int o = blockIdx.x;
  const int c = threadIdx.x;
  const float scale = 0.08838834764831844f;  // 1/sqrt(128)
  shK[c] = Wk[c*128 + o];      // Wk[m][o]  (column o)
  shO[c] = Wo[o*128 + c];      // Wo[o][m]
  __syncthreads();
  float aM = 0.f, aV = 0.f, tK = 0.f, bV = 0.f;
  for (int m = 0; m < 128; ++m) {
    aM += shK[m] * Wq[m*128 + c];   // M[o][c]
    aV += shO[m] * Wv[m*128 + c];   // Wv'[o][c]
    tK += shK[m] * bq[m];
    bV += shO[m] * bv[m];
  }
  wh[o*128 + c]         = (_Float16)(aM * scale);
  wh[16384 + o*128 + c] = (_Float16)aV;
  if (c == 0) { bf[o] = tK * scale; bf[128 + o] = bV + bo[o]; }
}

__device__ __forceinline__ f16x4 cvt4(f32x4 v, f32x4 b) {
  f16x4 r;
  r[0] = (_Float16)(v[0] + b[0]); r[1] = (_Float16)(v[1] + b[1]);
  r[2] = (_Float16)(v[2] + b[2]); r[3] = (_Float16)(v[3] + b[3]);
  return r;
}
__device__ __forceinline__ f16x4 cvt4z(f32x4 v) {
  f16x4 r;
  r[0] = (_Float16)v[0]; r[1] = (_Float16)v[1];
  r[2] = (_Float16)v[2]; r[3] = (_Float16)v[3];
  return r;
}

// XOR swizzle for Xt/Yt [256 rows][128 f16 cols], 256B rows, no padding.
// XOR folds row, row>>3 (stride-8-row accesses) and row>>5 (stride-64) so
// all phase patterns land >=8 distinct 16B chunks per 16 lanes. The XOR only
// permutes 16B chunks (byte bits 4..6), so 8B-aligned sub-writes stay intact.
__device__ __forceinline__ int xsw(int row, int col /*f16 units*/) {
  return ((row << 8) | (col << 1)) ^ (((row ^ (row >> 3) ^ (row >> 5)) & 7) << 4);
}

// ---- one 8-w half: P2(Y) -> P3(S+softmax) -> P5(U) -> P6(out) ----
// Expects Xt already populated for this half; enters with a barrier.
__device__ __forceinline__ void half_pass(
    char* XtB, char* YtB, _Float16* At,
    const _Float16* __restrict__ wh, const float* __restrict__ bfp,
    float* __restrict__ out, size_t pbaseh,
    int wv, int quad, int l15, const f16x8 (&wm)[4], f32x4 t4, float bb) {
  const f32x4 zz = {0.f, 0.f, 0.f, 0.f};
  const int mi = wv & 7, ni = wv >> 3;
  __syncthreads();   // Xt ready

  // ---- P2: Y = M~ X + t  -> Yt (rows = voxel d*8+p, cols = c1) ----
  {
    f32x4 aY[8] = {zz, zz, zz, zz, zz, zz, zz, zz};
#pragma unroll
    for (int kk = 0; kk < 4; ++kk) {
      const int co = kk*32 + quad*8;
#pragma unroll
      for (int nt = 0; nt < 8; ++nt) {
        const f16x8 bfv = *(const f16x8*)(XtB + xsw(ni*128 + nt*16 + l15, co));
        aY[nt] = MFMA(wm[kk], bfv, aY[nt]);
      }
    }
#pragma unroll
    for (int nt = 0; nt < 8; ++nt)
      *(f16x4*)(YtB + xsw(ni*128 + nt*16 + l15, mi*16 + quad*4)) = cvt4(aY[nt], t4);
  }
  __syncthreads();

  // ---- P3: S = X^T Y per pixel; wave = (pixel p, j-half tj); softmax -> At ----
  {
    const int p = wv & 7, tj = wv >> 3;
    f32x4 aS[2] = {zz, zz};
#pragma unroll
    for (int kk = 0; kk < 4; ++kk) {
      const int co = kk*32 + quad*8;
      const f16x8 by = *(const f16x8*)(YtB + xsw((tj*16 + l15)*8 + p, co));
#pragma unroll
      for (int ti = 0; ti < 2; ++ti) {
        const f16x8 ak = *(const f16x8*)(XtB + xsw((ti*16 + l15)*8 + p, co));
        aS[ti] = MFMA(ak, by, aS[ti]);
      }
    }
    // lane holds S[i = ti*16+quad*4+r][j = tj*16+l15]; reduce over i
    float mx = aS[0][0];
#pragma unroll
    for (int r = 1; r < 4; ++r) mx = fmaxf(mx, aS[0][r]);
#pragma unroll
    for (int r = 0; r < 4; ++r) mx = fmaxf(mx, aS[1][r]);
    mx = fmaxf(mx, __shfl_xor(mx, 16));
    mx = fmaxf(mx, __shfl_xor(mx, 32));
    float e[2][4];
    float den = 0.f;
#pragma unroll
    for (int ti = 0; ti < 2; ++ti)
#pragma unroll
      for (int r = 0; r < 4; ++r) { e[ti][r] = __expf(aS[ti][r] - mx); den += e[ti][r]; }
    den += __shfl_xor(den, 16);
    den += __shfl_xor(den, 32);
    const float rr = 1.0f / den;
#pragma unroll
    for (int ti = 0; ti < 2; ++ti) {
      f16x4 av;
#pragma unroll
      for (int r = 0; r < 4; ++r) av[r] = (_Float16)(e[ti][r] * rr);
      *(f16x4*)(At + (p*32 + tj*16 + l15)*40 + ti*16 + quad*4) = av;
    }
  }
  __syncthreads();

  // ---- P5: U = X A per pixel -> Yt (U^T rows = j*8+p); load Wv' frags ----
  f16x8 wp[4];
  {
#pragma unroll
    for (int kk = 0; kk < 4; ++kk)
      wp[kk] = *(const f16x8*)(wh + 16384 + (mi*16 + l15)*128 + kk*32 + quad*8);
    const int p = wv & 7, mg = wv >> 3;
    f16x8 bA[2];
#pragma unroll
    for (int tj = 0; tj < 2; ++tj)
      bA[tj] = *(const f16x8*)(At + (p*32 + tj*16 + l15)*40 + quad*8);
#pragma unroll
    for (int t2 = 0; t2 < 4; ++t2) {
      const int ms = mg*4 + t2;
      f16x8 ax;
#pragma unroll
      for (int jj = 0; jj < 8; ++jj)
        ax[jj] = *(const _Float16*)(XtB + xsw((quad*8 + jj)*8 + p, ms*16 + l15));
#pragma unroll
      for (int tj = 0; tj < 2; ++tj) {
        const f32x4 aU = MFMA(ax, bA[tj], zz);
        *(f16x4*)(YtB + xsw((tj*16 + l15)*8 + p, ms*16 + quad*4)) = cvt4z(aU);
      }
    }
  }
  __syncthreads();

  // ---- P6: out^T = U^T Wv'^T + b' + x : 32B stores; the other 32B half of
  // each 64B line is written by the lockstep SIBLING block in this same pass ----
  {
    const int oi = wv & 7, mg6 = wv >> 3;
    f32x4 acc[8] = {zz, zz, zz, zz, zz, zz, zz, zz};
#pragma unroll
    for (int kk = 0; kk < 4; ++kk) {
      const int co = kk*32 + quad*8;
#pragma unroll
      for (int mt = 0; mt < 8; ++mt) {
        const f16x8 av = *(const f16x8*)(YtB + xsw((mg6*8 + mt)*16 + l15, co));
        acc[mt] = MFMA(av, wp[kk], acc[mt]);
      }
    }
    const int o = oi*16 + l15;
    float* outp = out + pbaseh + (size_t)o*131072;
#pragma unroll
    for (int mt = 0; mt < 8; ++mt) {
      const int vox0 = (mg6*8 + mt)*16 + quad*4;   // voxel = d*8 + p
      const int d = vox0 >> 3;
      f32x4 vv;
#pragma unroll
      for (int r = 0; r < 4; ++r)
        vv[r] = acc[mt][r] + bb +
                (float)*(const _Float16*)(XtB + xsw(vox0 + r, o));
      *(f32x4*)(outp + (size_t)d*4096 + (vox0 & 7)) = vv;
    }
  }
  __syncthreads();   // Xt/Yt free for the next half's transpose
}

// ---------------- fused attention (2 passes/block, sibling-paired lines) ----------------
// grid = 512 blocks x 1024 thr, 2 rounds of 256. Block decodes:
//   sib = (bid>>3)&1, p_id = (bid>>4)*8 + (bid&7), round = bid>>8
// Pass A handles line-group L = round*256 + 2*p_id, pass B L+1; sib selects
// the 8-w half. Sibling blocks (bid, bid+8): same XCD, same round, same
// schedule -> their pass-A (resp. B) stores co-timed -> 64B lines complete
// in L2 (the R5-proven merge). Pass-B x loads issue right after pass-A's
// transpose (hidden under pass-A compute); pass-A writeback drains under
// pass B. LDS 148KB, 1 blk/CU lockstep.
__global__ __launch_bounds__(1024, 4) void attn_kernel(
    const float* __restrict__ x, const _Float16* __restrict__ wh,
    const float* __restrict__ bfp, float* __restrict__ out) {
  __shared__ __align__(16) char lds[151552];
  char* XtB = lds;                      // [256 r=d*8+p][128 c] f16, swizzled (64KB)
  char* YtB = lds + 65536;              // Y^T, later U^T, swizzled (64KB)
  _Float16* At = (_Float16*)(lds + 131072);  // [p*32+j][40 i] f16 (20KB)

  const int tid  = threadIdx.x;
  const int lane = tid & 63;
  const int wv   = tid >> 6;            // 0..15
  const int quad = lane >> 4;
  const int l15  = lane & 15;

  const int bid   = blockIdx.x;         // 0..511
  const int round = bid >> 8;
  const int sib   = (bid >> 3) & 1;
  const int p_id  = ((bid >> 4) & 15) * 8 + (bid & 7);   // 0..127
  const int LA    = round*256 + p_id*2; // line-group for pass A; B = LA+1

  auto lbase = [&](int L) -> size_t {
    const int b   = L >> 8;
    const int h   = (L >> 2) & 63;
    const int w16 = L & 3;
    return (size_t)b * 16777216u + (size_t)(h*64 + w16*16 + sib*8);
  };
  const size_t pbaseA = lbase(LA);
  const size_t pbaseB = lbase(LA + 1);

  // ---- pass-A x loads issued FIRST (longest latency) ----
  const int c4 = tid & 31;              // c-quad 0..31
  const int dd = tid >> 5;              // d 0..31
  const size_t toff = (size_t)c4*4*131072 + (size_t)dd*4096;
  const float* xgA = x + pbaseA + toff;
  const float* xgB = x + pbaseB + toff;
  f32x4 vA[4][2];
#pragma unroll
  for (int r = 0; r < 4; ++r)
#pragma unroll
    for (int i = 0; i < 2; ++i)
      vA[r][i] = *(const f32x4*)(xgA + (size_t)r*131072 + i*4);

  // ---- resident weight fragments + biases (overlap with x loads) ----
  const int mi = wv & 7;
  f16x8 wm[4];
#pragma unroll
  for (int kk = 0; kk < 4; ++kk)
    wm[kk] = *(const f16x8*)(wh + (mi*16 + l15)*128 + kk*32 + quad*8);
  const f32x4 t4 = *(const f32x4*)(bfp + mi*16 + quad*4);
  const float bb = bfp[128 + (wv & 7)*16 + l15];   // P6 bias (oi = wv&7)

  // ---- transpose A -> Xt (swizzled), 8 x ds_write_b64 ----
#pragma unroll
  for (int i = 0; i < 2; ++i)
#pragma unroll
    for (int p = 0; p < 4; ++p) {
      f16x4 t;
#pragma unroll
      for (int r = 0; r < 4; ++r) t[r] = (_Float16)vA[r][i][p];
      *(f16x4*)(XtB + xsw(dd*8 + i*4 + p, c4*4)) = t;
    }

  // ---- issue pass-B x loads now (hidden under pass-A compute; siblings
  // co-request the two halves of each B-line -> L2 read merge) ----
  f32x4 vB[4][2];
#pragma unroll
  for (int r = 0; r < 4; ++r)
#pragma unroll
    for (int i = 0; i < 2; ++i)
      vB[r][i] = *(const f32x4*)(xgB + (size_t)r*131072 + i*4);

  // ---- pass A ----
  half_pass(XtB, YtB, At, wh, bfp, out, pbaseA, wv, quad, l15, wm, t4, bb);

  // ---- transpose B -> Xt ----
#pragma unroll
  for (int i = 0; i < 2; ++i)
#pragma unroll
    for (int p = 0; p < 4; ++p) {
      f16x4 t;
#pragma unroll
      for (int r = 0; r < 4; ++r) t[r] = (_Float16)vB[r][i][p];
      *(f16x4*)(XtB + xsw(dd*8 + i*4 + p, c4*4)) = t;
    }

  // ---- pass B ----
  half_pass(XtB, YtB, At, wh, bfp, out, pbaseB, wv, quad, l15, wm, t4, bb);
}

extern "C" void kernel_launch(void* const* d_in, const int* in_sizes, int n_in,
                              void* d_out, int out_size, void* d_ws, size_t ws_size,
                              hipStream_t stream) {
  const float* x  = (const float*)d_in[0];
  const float* Wk = (const float*)d_in[1];
  const float* bk = (const float*)d_in[2];
  const float* Wq = (const float*)d_in[3];
  const float* bq = (const float*)d_in[4];
  const float* Wv = (const float*)d_in[5];
  const float* bv = (const float*)d_in[6];
  const float* Wo = (const float*)d_in[7];
  const float* bo = (const float*)d_in[8];
  float* out = (float*)d_out;
  _Float16* wh = (_Float16*)d_ws;
  float* bf = (float*)((char*)d_ws + 65536);

  prep_kernel<<<dim3(128), dim3(128), 0, stream>>>(Wk, bk, Wq, bq, Wv, bv, Wo, bo, wh, bf);
  attn_kernel<<<dim3(512), dim3(1024), 0, stream>>>(x, wh, bf, out);
}

// Round 10
// 349.625 us; speedup vs baseline: 1.5602x; 1.5375x over previous
//
#include <hip/hip_runtime.h>

typedef _Float16 f16x8 __attribute__((ext_vector_type(8)));
typedef _Float16 f16x4 __attribute__((ext_vector_type(4)));
typedef float    f32x4 __attribute__((ext_vector_type(4)));

#define MFMA(a,b,c) __builtin_amdgcn_mfma_f32_16x16x32_f16((a),(b),(c),0,0,0)

// ws layout (bytes): [0)      M~  f16 [128][128]  (scale * Wk^T Wq)
//                    [32768)  Wv' f16 [128][128]  (Wo @ Wv)
//                    [65536)  biases f32: t[128] = scale*Wk^T bq, b'[128] = Wo bv + bo
//                    [131072) Xg f16 [1024 g][256 rows=(d*8+p)][128 c]  (67.1 MB)
// Algebra: softmax over key-axis i is invariant to per-j offsets, so
//   S[i][j] = x_i^T (M x_j + t)  with M = scale*Wk^T Wq, t = scale*Wk^T bq
// (bk-only and constant terms drop). out = Wv' (X A) + b' + x.
//
// Design rules established R0-R9 (hard-won, 4 failed attempts):
//  - Partial 64B out-lines merge ONLY in the R5 regime: single-tile blocks of
//    uniform duration, fresh phase-aligned dispatch rounds, 32B granules from
//    lockstep sibling blocks (bid,bid+8). Persistent loops (R3,R6) and
//    two-pass blocks (R8,R9 -- even sibling-paired within pass) all produce
//    3.4x WRITE + RMW FETCH. Do not revisit multi-tile blocks.
//  - attn kernel below is the R5 measured optimum (87.5us, FETCH 34MB,
//    WRITE 143MB ~= ideal). Frozen.

// ---------------- prep: fold weights ----------------
__global__ __launch_bounds__(128) void prep_kernel(
    const float* __restrict__ Wk, const float* __restrict__ bk,
    const float* __restrict__ Wq, const float* __restrict__ bq,
    const float* __restrict__ Wv, const float* __restrict__ bv,
    const float* __restrict__ Wo, const float* __restrict__ bo,
    _Float16* __restrict__ wh, float* __restrict__ bf) {
  __shared__ float shK[128], shO[128];
  const int o = blockIdx.x;
  const int c = threadIdx.x;
  const float scale = 0.08838834764831844f;  // 1/sqrt(128)
  shK[c] = Wk[c*128 + o];      // Wk[m][o]  (column o)
  shO[c] = Wo[o*128 + c];      // Wo[o][m]
  __syncthreads();
  float aM = 0.f, aV = 0.f, tK = 0.f, bV = 0.f;
  for (int m = 0; m < 128; ++m) {
    aM += shK[m] * Wq[m*128 + c];   // M[o][c]
    aV += shO[m] * Wv[m*128 + c];   // Wv'[o][c]
    tK += shK[m] * bq[m];
    bV += shO[m] * bv[m];
  }
  wh[o*128 + c]         = (_Float16)(aM * scale);
  wh[16384 + o*128 + c] = (_Float16)aV;
  if (c == 0) { bf[o] = tK * scale; bf[128 + o] = bV + bo[o]; }
}

// ---------------- transpose v3: x fp32 [b,c,d,h,w] -> Xg f16 [g][d*8+p][c] ----------------
// grid = B*D*(H/4) = 1024 blocks, 256 thr; block loops 4 consecutive h with a
// double-buffered LDS tile (1 barrier/iter). Rationale: v2's one-shot blocks
// touched 128 DRAM rows for 256B each (row-buffer miss storm, 3.1TB/s);
// v3 streams 1KB per c-row per block and writes 2KB-contiguous Xg chunks.
// 4 blocks/CU (33.8KB LDS), all 1024 blocks in one phase-aligned round.
__global__ __launch_bounds__(256) void transpose_kernel(
    const float* __restrict__ x, _Float16* __restrict__ Xg) {
  __shared__ _Float16 Lt[2][64 * 132];       // [w][c], stride 132 (8B-aligned rows)
  const int bid = blockIdx.x;                // b(2) x d(32) x hq(16)
  const int hq = bid & 15, d = (bid >> 4) & 31, b = bid >> 9;
  const int tid = threadIdx.x;
  const int wq = tid & 15, cr = tid >> 4;    // cr in [0,16)
#pragma unroll
  for (int hi = 0; hi < 4; ++hi) {
    const int h = hq*4 + hi;
    const size_t rbase = (size_t)b*16777216u + (size_t)d*4096 + h*64;
    _Float16* L = Lt[hi & 1];
    // read: full 256B w-rows (consecutive hi -> sequential within each c-row)
#pragma unroll
    for (int pass = 0; pass < 2; ++pass) {
      const int base_c = pass*64 + cr*4;
      f32x4 v[4];
#pragma unroll
      for (int r = 0; r < 4; ++r)
        v[r] = *(const f32x4*)(x + rbase + (size_t)(base_c + r)*131072 + wq*4);
#pragma unroll
      for (int p = 0; p < 4; ++p) {
        f16x4 t;
#pragma unroll
        for (int r = 0; r < 4; ++r) t[r] = (_Float16)v[r][p];
        *(f16x4*)(L + (wq*4 + p)*132 + base_c) = t;
      }
    }
    __syncthreads();                         // L ready (other buffer free)
    // write: per w-row 256B contiguous; 8 rows (p=0..7) per group are
    // consecutive -> 2KB-contiguous chunks per (g,d)
    const int gbase = (b*64 + h)*8;
#pragma unroll
    for (int i = 0; i < 4; ++i) {
      const int idx = tid + i*256;           // 0..1023
      const int w = idx >> 4, ck = (idx & 15) * 8;
      const f16x8 v = *(const f16x8*)(L + w*132 + ck);
      *(f16x8*)(Xg + (size_t)(gbase + (w>>3))*32768 + (d*8 + (w&7))*128 + ck) = v;
    }
  }
}

__device__ __forceinline__ f16x4 cvt4(f32x4 v, f32x4 b) {
  f16x4 r;
  r[0] = (_Float16)(v[0] + b[0]); r[1] = (_Float16)(v[1] + b[1]);
  r[2] = (_Float16)(v[2] + b[2]); r[3] = (_Float16)(v[3] + b[3]);
  return r;
}
__device__ __forceinline__ f16x4 cvt4z(f32x4 v) {
  f16x4 r;
  r[0] = (_Float16)v[0]; r[1] = (_Float16)v[1];
  r[2] = (_Float16)v[2]; r[3] = (_Float16)v[3];
  return r;
}

// XOR swizzle for Xt/Yt [256 rows][128 f16 cols], 256B rows, no padding.
// XOR folds row, row>>3 (stride-8-row accesses) and row>>5 (stride-64) so
// all phase patterns land >=8 distinct 16B chunks per 16 lanes.
__device__ __forceinline__ int xsw(int row, int col /*f16 units*/) {
  return ((row << 8) | (col << 1)) ^ (((row ^ (row >> 3) ^ (row >> 5)) & 7) << 4);
}

// ---------------- fused attention (R5 optimum, frozen) ----------------
// grid = 1024 blocks x 1024 thr; 8 consecutive w per block -> each wave's quad
// pair stores 32B per 64B out-line; sibling blocks (bid,bid+8) are co-round +
// same-XCD and complete each line (R5: WRITE 143MB ~= ideal).
// LDS 148KB -> 1 block/CU: all CUs lockstep (the write-merge synchronizer).
__global__ __launch_bounds__(1024, 4) void attn_kernel(
    const _Float16* __restrict__ Xg, const _Float16* __restrict__ wh,
    const float* __restrict__ bfp, float* __restrict__ out) {
  __shared__ __align__(16) char lds[151552];
  char* XtB = lds;                      // [256 r=d*8+p][128 c] f16, swizzled (64KB)
  char* YtB = lds + 65536;              // Y^T, later U^T, swizzled (64KB)
  _Float16* At = (_Float16*)(lds + 131072);  // [p*32+j][40 i] f16 (20KB)

  const int tid  = threadIdx.x;
  const int lane = tid & 63;
  const int wv   = tid >> 6;            // 0..15
  const int quad = lane >> 4;
  const int l15  = lane & 15;

  const int bid = blockIdx.x;
  // sibling pairing: g and g^1 (the two halves of each 64B out-line) are
  // bids 8 apart -> same XCD (bid%8 equal), dispatched adjacently.
  const int g = (bid & ~15) | ((bid & 7) << 1) | ((bid >> 3) & 1);
  const int b   = g >> 9;
  const int rem = g & 511;
  const int h   = rem >> 3;
  const int wg  = rem & 7;
  const size_t pbase = (size_t)b * 16777216u + (size_t)(h*64 + wg*8);
  const f32x4 zz = {0.f, 0.f, 0.f, 0.f};

  // ---- prefetch M~ fragments + bias (in flight during P1) ----
  const int mi = wv & 7, ni = wv >> 3;
  f16x8 wm[4];
#pragma unroll
  for (int kk = 0; kk < 4; ++kk)
    wm[kk] = *(const f16x8*)(wh + (mi*16 + l15)*128 + kk*32 + quad*8);
  const f32x4 t4 = *(const f32x4*)(bfp + mi*16 + quad*4);

  // ---- P1: coalesced load of this group's 64KB f16 chunk -> Xt (swizzled) ----
  {
    const _Float16* src = Xg + (size_t)g * 32768;
#pragma unroll
    for (int i = 0; i < 4; ++i) {
      const int idx = tid + i*1024;          // 0..4095
      const int row = idx >> 4, ck = (idx & 15) * 8;
      const f16x8 v = *(const f16x8*)(src + row*128 + ck);
      *(f16x8*)(XtB + xsw(row, ck)) = v;
    }
  }
  __syncthreads();

  // ---- P2: Y = M~ X + t  -> Yt (rows = voxel d*8+p, cols = c1) ----
  {
    f32x4 aY[8] = {zz, zz, zz, zz, zz, zz, zz, zz};
#pragma unroll
    for (int kk = 0; kk < 4; ++kk) {
      const int co = kk*32 + quad*8;
#pragma unroll
      for (int nt = 0; nt < 8; ++nt) {
        const f16x8 bfv = *(const f16x8*)(XtB + xsw(ni*128 + nt*16 + l15, co));
        aY[nt] = MFMA(wm[kk], bfv, aY[nt]);
      }
    }
#pragma unroll
    for (int nt = 0; nt < 8; ++nt)
      *(f16x4*)(YtB + xsw(ni*128 + nt*16 + l15, mi*16 + quad*4)) = cvt4(aY[nt], t4);
  }
  __syncthreads();

  // ---- P3: S = X^T Y per pixel; wave = (pixel p, j-half tj); softmax -> At ----
  {
    const int p = wv & 7, tj = wv >> 3;
    f32x4 aS[2] = {zz, zz};
#pragma unroll
    for (int kk = 0; kk < 4; ++kk) {
      const int co = kk*32 + quad*8;
      const f16x8 by = *(const f16x8*)(YtB + xsw((tj*16 + l15)*8 + p, co));
#pragma unroll
      for (int ti = 0; ti < 2; ++ti) {
        const f16x8 ak = *(const f16x8*)(XtB + xsw((ti*16 + l15)*8 + p, co));
        aS[ti] = MFMA(ak, by, aS[ti]);
      }
    }
    // lane holds S[i = ti*16+quad*4+r][j = tj*16+l15]; reduce over i
    float mx = aS[0][0];
#pragma unroll
    for (int r = 1; r < 4; ++r) mx = fmaxf(mx, aS[0][r]);
#pragma unroll
    for (int r = 0; r < 4; ++r) mx = fmaxf(mx, aS[1][r]);
    mx = fmaxf(mx, __shfl_xor(mx, 16));
    mx = fmaxf(mx, __shfl_xor(mx, 32));
    float e[2][4];
    float den = 0.f;
#pragma unroll
    for (int ti = 0; ti < 2; ++ti)
#pragma unroll
      for (int r = 0; r < 4; ++r) { e[ti][r] = __expf(aS[ti][r] - mx); den += e[ti][r]; }
    den += __shfl_xor(den, 16);
    den += __shfl_xor(den, 32);
    const float rr = 1.0f / den;
#pragma unroll
    for (int ti = 0; ti < 2; ++ti) {
      f16x4 av;
#pragma unroll
      for (int r = 0; r < 4; ++r) av[r] = (_Float16)(e[ti][r] * rr);
      *(f16x4*)(At + (p*32 + tj*16 + l15)*40 + ti*16 + quad*4) = av;
    }
  }
  __syncthreads();

  // ---- P5: U = X A per pixel -> Yt (U^T rows = j*8+p); load Wv' frags ----
  f16x8 wp[4];
  {
#pragma unroll
    for (int kk = 0; kk < 4; ++kk)
      wp[kk] = *(const f16x8*)(wh + 16384 + (mi*16 + l15)*128 + kk*32 + quad*8);
    const int p = wv & 7, mg = wv >> 3;
    f16x8 bA[2];
#pragma unroll
    for (int tj = 0; tj < 2; ++tj)
      bA[tj] = *(const f16x8*)(At + (p*32 + tj*16 + l15)*40 + quad*8);
#pragma unroll
    for (int t2 = 0; t2 < 4; ++t2) {
      const int ms = mg*4 + t2;
      f16x8 ax;
#pragma unroll
      for (int jj = 0; jj < 8; ++jj)
        ax[jj] = *(const _Float16*)(XtB + xsw((quad*8 + jj)*8 + p, ms*16 + l15));
#pragma unroll
      for (int tj = 0; tj < 2; ++tj) {
        const f32x4 aU = MFMA(ax, bA[tj], zz);
        *(f16x4*)(YtB + xsw((tj*16 + l15)*8 + p, ms*16 + quad*4)) = cvt4z(aU);
      }
    }
  }
  __syncthreads();

  // ---- P6: out^T = U^T Wv'^T + b' + x : 32B/line stores (quad pairs) ----
  {
    const int oi = wv & 7, mg6 = wv >> 3;
    f32x4 acc[8] = {zz, zz, zz, zz, zz, zz, zz, zz};
#pragma unroll
    for (int kk = 0; kk < 4; ++kk) {
      const int co = kk*32 + quad*8;
#pragma unroll
      for (int mt = 0; mt < 8; ++mt) {
        const f16x8 av = *(const f16x8*)(YtB + xsw((mg6*8 + mt)*16 + l15, co));
        acc[mt] = MFMA(av, wp[kk], acc[mt]);
      }
    }
    const int o = oi*16 + l15;
    const float bb = bfp[128 + o];
    float* outp = out + pbase + (size_t)o*131072;
#pragma unroll
    for (int mt = 0; mt < 8; ++mt) {
      const int vox0 = (mg6*8 + mt)*16 + quad*4;   // voxel = d*8 + p
      const int d = vox0 >> 3;
      f32x4 v;
#pragma unroll
      for (int r = 0; r < 4; ++r)
        v[r] = acc[mt][r] + bb +
               (float)*(const _Float16*)(XtB + xsw(vox0 + r, o));
      *(f32x4*)(outp + (size_t)d*4096 + (vox0 & 7)) = v;
    }
  }
}

extern "C" void kernel_launch(void* const* d_in, const int* in_sizes, int n_in,
                              void* d_out, int out_size, void* d_ws, size_t ws_size,
                              hipStream_t stream) {
  const float* x  = (const float*)d_in[0];
  const float* Wk = (const float*)d_in[1];
  const float* bk = (const float*)d_in[2];
  const float* Wq = (const float*)d_in[3];
  const float* bq = (const float*)d_in[4];
  const float* Wv = (const float*)d_in[5];
  const float* bv = (const float*)d_in[6];
  const float* Wo = (const float*)d_in[7];
  const float* bo = (const float*)d_in[8];
  float* out = (float*)d_out;
  _Float16* wh = (_Float16*)d_ws;
  float* bf = (float*)((char*)d_ws + 65536);
  _Float16* Xg = (_Float16*)((char*)d_ws + 131072);  // needs 67.1 MB of ws

  prep_kernel<<<dim3(128), dim3(128), 0, stream>>>(Wk, bk, Wq, bq, Wv, bv, Wo, bo, wh, bf);
  transpose_kernel<<<dim3(1024), dim3(256), 0, stream>>>(x, Xg);
  attn_kernel<<<dim3(1024), dim3(1024), 0, stream>>>(Xg, wh, bf, out);
}

// Round 11
// 348.359 us; speedup vs baseline: 1.5659x; 1.0036x over previous
//
#include <hip/hip_runtime.h>

typedef _Float16 f16x8 __attribute__((ext_vector_type(8)));
typedef _Float16 f16x4 __attribute__((ext_vector_type(4)));
typedef float    f32x4 __attribute__((ext_vector_type(4)));

#define MFMA(a,b,c) __builtin_amdgcn_mfma_f32_16x16x32_f16((a),(b),(c),0,0,0)

// ws layout (bytes): [0)      M~  f16 [128][128]  (scale * Wk^T Wq)
//                    [32768)  Wv' f16 [128][128]  (Wo @ Wv)
//                    [65536)  biases f32: t[128] = scale*Wk^T bq, b'[128] = Wo bv + bo
//                    [131072) Xg f16 [1024 g][256 rows=(d*8+p)][128 c]  (67.1 MB)
// Algebra: softmax over key-axis i is invariant to per-j offsets, so
//   S[i][j] = x_i^T (M x_j + t)  with M = scale*Wk^T Wq, t = scale*Wk^T bq
// (bk-only and constant terms drop). out = Wv' (X A) + b' + x.
//
// Design rules established R0-R10 (hard-won):
//  - Partial 64B out-lines merge ONLY with co-timed 32B halves: lockstep
//    sibling blocks (R5) or lockstep waves of one block. Persistent loops
//    (R3,R6) and two-pass blocks (R8,R9) always produce 3.4x WRITE + RMW.
//  - attn kernel = R5 measured optimum (87.5-88us, FETCH 34MB, WRITE 143MB
//    ~= ideal). FROZEN — 4 restructuring attempts all regressed.
//  - ~186us of dur_us is harness workspace re-poison (2x 512MiB fills @88us,
//    seen in R10 profile) — not reducible by kernel design.
//  - transpose v2 (LDS-staged) == v3 (h-looped) ~= 65us @ 3.1TB/s; v4 below
//    tests the LDS-round-trip hypothesis by deleting LDS entirely.

// ---------------- prep: fold weights ----------------
__global__ __launch_bounds__(128) void prep_kernel(
    const float* __restrict__ Wk, const float* __restrict__ bk,
    const float* __restrict__ Wq, const float* __restrict__ bq,
    const float* __restrict__ Wv, const float* __restrict__ bv,
    const float* __restrict__ Wo, const float* __restrict__ bo,
    _Float16* __restrict__ wh, float* __restrict__ bf) {
  __shared__ float shK[128], shO[128];
  const int o = blockIdx.x;
  const int c = threadIdx.x;
  const float scale = 0.08838834764831844f;  // 1/sqrt(128)
  shK[c] = Wk[c*128 + o];      // Wk[m][o]  (column o)
  shO[c] = Wo[o*128 + c];      // Wo[o][m]
  __syncthreads();
  float aM = 0.f, aV = 0.f, tK = 0.f, bV = 0.f;
  for (int m = 0; m < 128; ++m) {
    aM += shK[m] * Wq[m*128 + c];   // M[o][c]
    aV += shO[m] * Wv[m*128 + c];   // Wv'[o][c]
    tK += shK[m] * bq[m];
    bV += shO[m] * bv[m];
  }
  wh[o*128 + c]         = (_Float16)(aM * scale);
  wh[16384 + o*128 + c] = (_Float16)aV;
  if (c == 0) { bf[o] = tK * scale; bf[128 + o] = bV + bo[o]; }
}

// ---------------- transpose v4: register-only, no LDS ----------------
// grid = B*D*H = 4096 blocks, 256 thr. Thread reads 4 c x 4 w (4 x f32x4),
// transposes 4x4 in registers, stores f16x4 (8B) straight to Xg. Per store
// instruction, the wave's 4 cr-groups assemble 32B sectors per voxel-row;
// the other 32B of each 64B line comes from the next wave of the SAME block
// (co-issued -> L2 merge, the R5-proven lockstep regime). No LDS, no barrier.
__global__ __launch_bounds__(256) void transpose_kernel(
    const float* __restrict__ x, _Float16* __restrict__ Xg) {
  const int bid = blockIdx.x;
  const int h = bid & 63, d = (bid >> 6) & 31, b = bid >> 11;
  const int tid = threadIdx.x;
  const int wq = tid & 15, cr = tid >> 4;    // w-quad 0..15, c-quad 0..15
  const size_t rbase = (size_t)b*16777216u + (size_t)d*4096 + h*64;
  const int gbase = (b*64 + h)*8;            // 8 groups per (b,h)
#pragma unroll
  for (int pass = 0; pass < 2; ++pass) {
    const int base_c = pass*64 + cr*4;
    f32x4 v[4];
#pragma unroll
    for (int r = 0; r < 4; ++r)
      v[r] = *(const f32x4*)(x + rbase + (size_t)(base_c + r)*131072 + wq*4);
#pragma unroll
    for (int p = 0; p < 4; ++p) {
      const int w = wq*4 + p;
      f16x4 t;
#pragma unroll
      for (int r = 0; r < 4; ++r) t[r] = (_Float16)v[r][p];
      *(f16x4*)(Xg + (size_t)(gbase + (w >> 3))*32768
                   + (size_t)(d*8 + (w & 7))*128 + base_c) = t;
    }
  }
}

__device__ __forceinline__ f16x4 cvt4(f32x4 v, f32x4 b) {
  f16x4 r;
  r[0] = (_Float16)(v[0] + b[0]); r[1] = (_Float16)(v[1] + b[1]);
  r[2] = (_Float16)(v[2] + b[2]); r[3] = (_Float16)(v[3] + b[3]);
  return r;
}
__device__ __forceinline__ f16x4 cvt4z(f32x4 v) {
  f16x4 r;
  r[0] = (_Float16)v[0]; r[1] = (_Float16)v[1];
  r[2] = (_Float16)v[2]; r[3] = (_Float16)v[3];
  return r;
}

// XOR swizzle for Xt/Yt [256 rows][128 f16 cols], 256B rows, no padding.
// XOR folds row, row>>3 (stride-8-row accesses) and row>>5 (stride-64) so
// all phase patterns land >=8 distinct 16B chunks per 16 lanes.
__device__ __forceinline__ int xsw(int row, int col /*f16 units*/) {
  return ((row << 8) | (col << 1)) ^ (((row ^ (row >> 3) ^ (row >> 5)) & 7) << 4);
}

// ---------------- fused attention (R5 optimum, frozen) ----------------
// grid = 1024 blocks x 1024 thr; 8 consecutive w per block -> each wave's quad
// pair stores 32B per 64B out-line; sibling blocks (bid,bid+8) are co-round +
// same-XCD and complete each line (R5: WRITE 143MB ~= ideal).
// LDS 148KB -> 1 block/CU: all CUs lockstep (the write-merge synchronizer).
__global__ __launch_bounds__(1024, 4) void attn_kernel(
    const _Float16* __restrict__ Xg, const _Float16* __restrict__ wh,
    const float* __restrict__ bfp, float* __restrict__ out) {
  __shared__ __align__(16) char lds[151552];
  char* XtB = lds;                      // [256 r=d*8+p][128 c] f16, swizzled (64KB)
  char* YtB = lds + 65536;              // Y^T, later U^T, swizzled (64KB)
  _Float16* At = (_Float16*)(lds + 131072);  // [p*32+j][40 i] f16 (20KB)

  const int tid  = threadIdx.x;
  const int lane = tid & 63;
  const int wv   = tid >> 6;            // 0..15
  const int quad = lane >> 4;
  const int l15  = lane & 15;

  const int bid = blockIdx.x;
  // sibling pairing: g and g^1 (the two halves of each 64B out-line) are
  // bids 8 apart -> same XCD (bid%8 equal), dispatched adjacently.
  const int g = (bid & ~15) | ((bid & 7) << 1) | ((bid >> 3) & 1);
  const int b   = g >> 9;
  const int rem = g & 511;
  const int h   = rem >> 3;
  const int wg  = rem & 7;
  const size_t pbase = (size_t)b * 16777216u + (size_t)(h*64 + wg*8);
  const f32x4 zz = {0.f, 0.f, 0.f, 0.f};

  // ---- prefetch M~ fragments + bias (in flight during P1) ----
  const int mi = wv & 7, ni = wv >> 3;
  f16x8 wm[4];
#pragma unroll
  for (int kk = 0; kk < 4; ++kk)
    wm[kk] = *(const f16x8*)(wh + (mi*16 + l15)*128 + kk*32 + quad*8);
  const f32x4 t4 = *(const f32x4*)(bfp + mi*16 + quad*4);

  // ---- P1: coalesced load of this group's 64KB f16 chunk -> Xt (swizzled) ----
  {
    const _Float16* src = Xg + (size_t)g * 32768;
#pragma unroll
    for (int i = 0; i < 4; ++i) {
      const int idx = tid + i*1024;          // 0..4095
      const int row = idx >> 4, ck = (idx & 15) * 8;
      const f16x8 v = *(const f16x8*)(src + row*128 + ck);
      *(f16x8*)(XtB + xsw(row, ck)) = v;
    }
  }
  __syncthreads();

  // ---- P2: Y = M~ X + t  -> Yt (rows = voxel d*8+p, cols = c1) ----
  {
    f32x4 aY[8] = {zz, zz, zz, zz, zz, zz, zz, zz};
#pragma unroll
    for (int kk = 0; kk < 4; ++kk) {
      const int co = kk*32 + quad*8;
#pragma unroll
      for (int nt = 0; nt < 8; ++nt) {
        const f16x8 bfv = *(const f16x8*)(XtB + xsw(ni*128 + nt*16 + l15, co));
        aY[nt] = MFMA(wm[kk], bfv, aY[nt]);
      }
    }
#pragma unroll
    for (int nt = 0; nt < 8; ++nt)
      *(f16x4*)(YtB + xsw(ni*128 + nt*16 + l15, mi*16 + quad*4)) = cvt4(aY[nt], t4);
  }
  __syncthreads();

  // ---- P3: S = X^T Y per pixel; wave = (pixel p, j-half tj); softmax -> At ----
  {
    const int p = wv & 7, tj = wv >> 3;
    f32x4 aS[2] = {zz, zz};
#pragma unroll
    for (int kk = 0; kk < 4; ++kk) {
      const int co = kk*32 + quad*8;
      const f16x8 by = *(const f16x8*)(YtB + xsw((tj*16 + l15)*8 + p, co));
#pragma unroll
      for (int ti = 0; ti < 2; ++ti) {
        const f16x8 ak = *(const f16x8*)(XtB + xsw((ti*16 + l15)*8 + p, co));
        aS[ti] = MFMA(ak, by, aS[ti]);
      }
    }
    // lane holds S[i = ti*16+quad*4+r][j = tj*16+l15]; reduce over i
    float mx = aS[0][0];
#pragma unroll
    for (int r = 1; r < 4; ++r) mx = fmaxf(mx, aS[0][r]);
#pragma unroll
    for (int r = 0; r < 4; ++r) mx = fmaxf(mx, aS[1][r]);
    mx = fmaxf(mx, __shfl_xor(mx, 16));
    mx = fmaxf(mx, __shfl_xor(mx, 32));
    float e[2][4];
    float den = 0.f;
#pragma unroll
    for (int ti = 0; ti < 2; ++ti)
#pragma unroll
      for (int r = 0; r < 4; ++r) { e[ti][r] = __expf(aS[ti][r] - mx); den += e[ti][r]; }
    den += __shfl_xor(den, 16);
    den += __shfl_xor(den, 32);
    const float rr = 1.0f / den;
#pragma unroll
    for (int ti = 0; ti < 2; ++ti) {
      f16x4 av;
#pragma unroll
      for (int r = 0; r < 4; ++r) av[r] = (_Float16)(e[ti][r] * rr);
      *(f16x4*)(At + (p*32 + tj*16 + l15)*40 + ti*16 + quad*4) = av;
    }
  }
  __syncthreads();

  // ---- P5: U = X A per pixel -> Yt (U^T rows = j*8+p); load Wv' frags ----
  f16x8 wp[4];
  {
#pragma unroll
    for (int kk = 0; kk < 4; ++kk)
      wp[kk] = *(const f16x8*)(wh + 16384 + (mi*16 + l15)*128 + kk*32 + quad*8);
    const int p = wv & 7, mg = wv >> 3;
    f16x8 bA[2];
#pragma unroll
    for (int tj = 0; tj < 2; ++tj)
      bA[tj] = *(const f16x8*)(At + (p*32 + tj*16 + l15)*40 + quad*8);
#pragma unroll
    for (int t2 = 0; t2 < 4; ++t2) {
      const int ms = mg*4 + t2;
      f16x8 ax;
#pragma unroll
      for (int jj = 0; jj < 8; ++jj)
        ax[jj] = *(const _Float16*)(XtB + xsw((quad*8 + jj)*8 + p, ms*16 + l15));
#pragma unroll
      for (int tj = 0; tj < 2; ++tj) {
        const f32x4 aU = MFMA(ax, bA[tj], zz);
        *(f16x4*)(YtB + xsw((tj*16 + l15)*8 + p, ms*16 + quad*4)) = cvt4z(aU);
      }
    }
  }
  __syncthreads();

  // ---- P6: out^T = U^T Wv'^T + b' + x : 32B/line stores (quad pairs) ----
  {
    const int oi = wv & 7, mg6 = wv >> 3;
    f32x4 acc[8] = {zz, zz, zz, zz, zz, zz, zz, zz};
#pragma unroll
    for (int kk = 0; kk < 4; ++kk) {
      const int co = kk*32 + quad*8;
#pragma unroll
      for (int mt = 0; mt < 8; ++mt) {
        const f16x8 av = *(const f16x8*)(YtB + xsw((mg6*8 + mt)*16 + l15, co));
        acc[mt] = MFMA(av, wp[kk], acc[mt]);
      }
    }
    const int o = oi*16 + l15;
    const float bb = bfp[128 + o];
    float* outp = out + pbase + (size_t)o*131072;
#pragma unroll
    for (int mt = 0; mt < 8; ++mt) {
      const int vox0 = (mg6*8 + mt)*16 + quad*4;   // voxel = d*8 + p
      const int d = vox0 >> 3;
      f32x4 v;
#pragma unroll
      for (int r = 0; r < 4; ++r)
        v[r] = acc[mt][r] + bb +
               (float)*(const _Float16*)(XtB + xsw(vox0 + r, o));
      *(f32x4*)(outp + (size_t)d*4096 + (vox0 & 7)) = v;
    }
  }
}

extern "C" void kernel_launch(void* const* d_in, const int* in_sizes, int n_in,
                              void* d_out, int out_size, void* d_ws, size_t ws_size,
                              hipStream_t stream) {
  const float* x  = (const float*)d_in[0];
  const float* Wk = (const float*)d_in[1];
  const float* bk = (const float*)d_in[2];
  const float* Wq = (const float*)d_in[3];
  const float* bq = (const float*)d_in[4];
  const float* Wv = (const float*)d_in[5];
  const float* bv = (const float*)d_in[6];
  const float* Wo = (const float*)d_in[7];
  const float* bo = (const float*)d_in[8];
  float* out = (float*)d_out;
  _Float16* wh = (_Float16*)d_ws;
  float* bf = (float*)((char*)d_ws + 65536);
  _Float16* Xg = (_Float16*)((char*)d_ws + 131072);  // needs 67.1 MB of ws

  prep_kernel<<<dim3(128), dim3(128), 0, stream>>>(Wk, bk, Wq, bq, Wv, bv, Wo, bo, wh, bf);
  transpose_kernel<<<dim3(4096), dim3(256), 0, stream>>>(x, Xg);
  attn_kernel<<<dim3(1024), dim3(1024), 0, stream>>>(Xg, wh, bf, out);
}

// Round 12
// 335.696 us; speedup vs baseline: 1.6250x; 1.0377x over previous
//
#include <hip/hip_runtime.h>

typedef _Float16 f16x8 __attribute__((ext_vector_type(8)));
typedef _Float16 f16x4 __attribute__((ext_vector_type(4)));
typedef float    f32x4 __attribute__((ext_vector_type(4)));

#define MFMA(a,b,c) __builtin_amdgcn_mfma_f32_16x16x32_f16((a),(b),(c),0,0,0)

// ws layout (bytes): [0)      M~  f16 [128][128]  (scale * Wk^T Wq)
//                    [32768)  Wv' f16 [128][128]  (Wo @ Wv)
//                    [65536)  biases f32: t[128] = scale*Wk^T bq, b'[128] = Wo bv + bo
//                    [131072) Xg f16 [1024 g][256 rows=(d*8+p)][128 c]  (67.1 MB)
// Algebra: softmax over key-axis i is invariant to per-j offsets, so
//   S[i][j] = x_i^T (M x_j + t)  with M = scale*Wk^T Wq, t = scale*Wk^T bq
// (bk-only and constant terms drop). out = Wv' (X A) + b' + x.
//
// Design rules established R0-R11 (hard-won):
//  - Partial 64B out-lines merge ONLY with co-timed 32B halves: lockstep
//    sibling blocks (R5) or lockstep waves of one block. Persistent loops
//    (R3,R6) and two-pass blocks (R8,R9) always produce 3.4x WRITE + RMW.
//  - attn kernel = R5 measured optimum (87.5-89us, FETCH 34MB, WRITE 143MB
//    ~= ideal). FROZEN — 4 restructuring attempts all regressed.
//  - transpose: v2 (LDS) == v3 (h-loop) == v4 (register-only) ~= 65us ->
//    DRAM-pattern-limited (mixed 134MB read + 67MB write @ ~3.1TB/s).
//  - ~188us of dur_us is harness workspace re-poison (2x 512MiB fills @88us)
//    — not reducible by kernel design.
// R12: consolidation — prep merged into the transpose dispatch (one launch);
// non-temporal x loads (read-once data stays out of L2/L3, preserving Xg
// residency for attn's P1).

// ---------------- fused prep + transpose ----------------
// grid = 4096 + 64 blocks, 256 thr.
// Blocks 0..4095: transpose v4 (register-only). Block reads 4c x 4w per
//   thread (f32x4, non-temporal), transposes in registers, stores f16x4 (8B)
//   to Xg; each wave covers 32B per Xg line, the other 32B comes from the
//   co-resident sibling wave of the same block (lockstep merge).
// Blocks 4096..4159: prep — fold weights; 2 output rows per block.
__global__ __launch_bounds__(256) void prep_transpose_kernel(
    const float* __restrict__ x, _Float16* __restrict__ Xg,
    const float* __restrict__ Wk, const float* __restrict__ bk,
    const float* __restrict__ Wq, const float* __restrict__ bq,
    const float* __restrict__ Wv, const float* __restrict__ bv,
    const float* __restrict__ Wo, const float* __restrict__ bo,
    _Float16* __restrict__ wh, float* __restrict__ bf) {
  const int bid = blockIdx.x;
  const int tid = threadIdx.x;
  if (bid >= 4096) {
    // ---- prep path: o = (bid-4096)*2 + half ----
    __shared__ float shK[2][128], shO[2][128];
    const int half = tid >> 7;
    const int c = tid & 127;
    const int o = (bid - 4096)*2 + half;
    const float scale = 0.08838834764831844f;  // 1/sqrt(128)
    shK[half][c] = Wk[c*128 + o];      // Wk[m][o]  (column o)
    shO[half][c] = Wo[o*128 + c];      // Wo[o][m]
    __syncthreads();
    float aM = 0.f, aV = 0.f, tK = 0.f, bV = 0.f;
    for (int m = 0; m < 128; ++m) {
      aM += shK[half][m] * Wq[m*128 + c];   // M[o][c]
      aV += shO[half][m] * Wv[m*128 + c];   // Wv'[o][c]
      tK += shK[half][m] * bq[m];
      bV += shO[half][m] * bv[m];
    }
    wh[o*128 + c]         = (_Float16)(aM * scale);
    wh[16384 + o*128 + c] = (_Float16)aV;
    if (c == 0) { bf[o] = tK * scale; bf[128 + o] = bV + bo[o]; }
    return;
  }
  // ---- transpose path ----
  const int h = bid & 63, d = (bid >> 6) & 31, b = bid >> 11;
  const int wq = tid & 15, cr = tid >> 4;    // w-quad 0..15, c-quad 0..15
  const size_t rbase = (size_t)b*16777216u + (size_t)d*4096 + h*64;
  const int gbase = (b*64 + h)*8;            // 8 groups per (b,h)
#pragma unroll
  for (int pass = 0; pass < 2; ++pass) {
    const int base_c = pass*64 + cr*4;
    f32x4 v[4];
#pragma unroll
    for (int r = 0; r < 4; ++r)
      v[r] = __builtin_nontemporal_load(
               (const f32x4*)(x + rbase + (size_t)(base_c + r)*131072 + wq*4));
#pragma unroll
    for (int p = 0; p < 4; ++p) {
      const int w = wq*4 + p;
      f16x4 t;
#pragma unroll
      for (int r = 0; r < 4; ++r) t[r] = (_Float16)v[r][p];
      *(f16x4*)(Xg + (size_t)(gbase + (w >> 3))*32768
                   + (size_t)(d*8 + (w & 7))*128 + base_c) = t;
    }
  }
}

__device__ __forceinline__ f16x4 cvt4(f32x4 v, f32x4 b) {
  f16x4 r;
  r[0] = (_Float16)(v[0] + b[0]); r[1] = (_Float16)(v[1] + b[1]);
  r[2] = (_Float16)(v[2] + b[2]); r[3] = (_Float16)(v[3] + b[3]);
  return r;
}
__device__ __forceinline__ f16x4 cvt4z(f32x4 v) {
  f16x4 r;
  r[0] = (_Float16)v[0]; r[1] = (_Float16)v[1];
  r[2] = (_Float16)v[2]; r[3] = (_Float16)v[3];
  return r;
}

// XOR swizzle for Xt/Yt [256 rows][128 f16 cols], 256B rows, no padding.
// XOR folds row, row>>3 (stride-8-row accesses) and row>>5 (stride-64) so
// all phase patterns land >=8 distinct 16B chunks per 16 lanes.
__device__ __forceinline__ int xsw(int row, int col /*f16 units*/) {
  return ((row << 8) | (col << 1)) ^ (((row ^ (row >> 3) ^ (row >> 5)) & 7) << 4);
}

// ---------------- fused attention (R5 optimum, frozen) ----------------
// grid = 1024 blocks x 1024 thr; 8 consecutive w per block -> each wave's quad
// pair stores 32B per 64B out-line; sibling blocks (bid,bid+8) are co-round +
// same-XCD and complete each line (R5: WRITE 143MB ~= ideal).
// LDS 148KB -> 1 block/CU: all CUs lockstep (the write-merge synchronizer).
__global__ __launch_bounds__(1024, 4) void attn_kernel(
    const _Float16* __restrict__ Xg, const _Float16* __restrict__ wh,
    const float* __restrict__ bfp, float* __restrict__ out) {
  __shared__ __align__(16) char lds[151552];
  char* XtB = lds;                      // [256 r=d*8+p][128 c] f16, swizzled (64KB)
  char* YtB = lds + 65536;              // Y^T, later U^T, swizzled (64KB)
  _Float16* At = (_Float16*)(lds + 131072);  // [p*32+j][40 i] f16 (20KB)

  const int tid  = threadIdx.x;
  const int lane = tid & 63;
  const int wv   = tid >> 6;            // 0..15
  const int quad = lane >> 4;
  const int l15  = lane & 15;

  const int bid = blockIdx.x;
  // sibling pairing: g and g^1 (the two halves of each 64B out-line) are
  // bids 8 apart -> same XCD (bid%8 equal), dispatched adjacently.
  const int g = (bid & ~15) | ((bid & 7) << 1) | ((bid >> 3) & 1);
  const int b   = g >> 9;
  const int rem = g & 511;
  const int h   = rem >> 3;
  const int wg  = rem & 7;
  const size_t pbase = (size_t)b * 16777216u + (size_t)(h*64 + wg*8);
  const f32x4 zz = {0.f, 0.f, 0.f, 0.f};

  // ---- prefetch M~ fragments + bias (in flight during P1) ----
  const int mi = wv & 7, ni = wv >> 3;
  f16x8 wm[4];
#pragma unroll
  for (int kk = 0; kk < 4; ++kk)
    wm[kk] = *(const f16x8*)(wh + (mi*16 + l15)*128 + kk*32 + quad*8);
  const f32x4 t4 = *(const f32x4*)(bfp + mi*16 + quad*4);

  // ---- P1: coalesced load of this group's 64KB f16 chunk -> Xt (swizzled) ----
  {
    const _Float16* src = Xg + (size_t)g * 32768;
#pragma unroll
    for (int i = 0; i < 4; ++i) {
      const int idx = tid + i*1024;          // 0..4095
      const int row = idx >> 4, ck = (idx & 15) * 8;
      const f16x8 v = *(const f16x8*)(src + row*128 + ck);
      *(f16x8*)(XtB + xsw(row, ck)) = v;
    }
  }
  __syncthreads();

  // ---- P2: Y = M~ X + t  -> Yt (rows = voxel d*8+p, cols = c1) ----
  {
    f32x4 aY[8] = {zz, zz, zz, zz, zz, zz, zz, zz};
#pragma unroll
    for (int kk = 0; kk < 4; ++kk) {
      const int co = kk*32 + quad*8;
#pragma unroll
      for (int nt = 0; nt < 8; ++nt) {
        const f16x8 bfv = *(const f16x8*)(XtB + xsw(ni*128 + nt*16 + l15, co));
        aY[nt] = MFMA(wm[kk], bfv, aY[nt]);
      }
    }
#pragma unroll
    for (int nt = 0; nt < 8; ++nt)
      *(f16x4*)(YtB + xsw(ni*128 + nt*16 + l15, mi*16 + quad*4)) = cvt4(aY[nt], t4);
  }
  __syncthreads();

  // ---- P3: S = X^T Y per pixel; wave = (pixel p, j-half tj); softmax -> At ----
  {
    const int p = wv & 7, tj = wv >> 3;
    f32x4 aS[2] = {zz, zz};
#pragma unroll
    for (int kk = 0; kk < 4; ++kk) {
      const int co = kk*32 + quad*8;
      const f16x8 by = *(const f16x8*)(YtB + xsw((tj*16 + l15)*8 + p, co));
#pragma unroll
      for (int ti = 0; ti < 2; ++ti) {
        const f16x8 ak = *(const f16x8*)(XtB + xsw((ti*16 + l15)*8 + p, co));
        aS[ti] = MFMA(ak, by, aS[ti]);
      }
    }
    // lane holds S[i = ti*16+quad*4+r][j = tj*16+l15]; reduce over i
    float mx = aS[0][0];
#pragma unroll
    for (int r = 1; r < 4; ++r) mx = fmaxf(mx, aS[0][r]);
#pragma unroll
    for (int r = 0; r < 4; ++r) mx = fmaxf(mx, aS[1][r]);
    mx = fmaxf(mx, __shfl_xor(mx, 16));
    mx = fmaxf(mx, __shfl_xor(mx, 32));
    float e[2][4];
    float den = 0.f;
#pragma unroll
    for (int ti = 0; ti < 2; ++ti)
#pragma unroll
      for (int r = 0; r < 4; ++r) { e[ti][r] = __expf(aS[ti][r] - mx); den += e[ti][r]; }
    den += __shfl_xor(den, 16);
    den += __shfl_xor(den, 32);
    const float rr = 1.0f / den;
#pragma unroll
    for (int ti = 0; ti < 2; ++ti) {
      f16x4 av;
#pragma unroll
      for (int r = 0; r < 4; ++r) av[r] = (_Float16)(e[ti][r] * rr);
      *(f16x4*)(At + (p*32 + tj*16 + l15)*40 + ti*16 + quad*4) = av;
    }
  }
  __syncthreads();

  // ---- P5: U = X A per pixel -> Yt (U^T rows = j*8+p); load Wv' frags ----
  f16x8 wp[4];
  {
#pragma unroll
    for (int kk = 0; kk < 4; ++kk)
      wp[kk] = *(const f16x8*)(wh + 16384 + (mi*16 + l15)*128 + kk*32 + quad*8);
    const int p = wv & 7, mg = wv >> 3;
    f16x8 bA[2];
#pragma unroll
    for (int tj = 0; tj < 2; ++tj)
      bA[tj] = *(const f16x8*)(At + (p*32 + tj*16 + l15)*40 + quad*8);
#pragma unroll
    for (int t2 = 0; t2 < 4; ++t2) {
      const int ms = mg*4 + t2;
      f16x8 ax;
#pragma unroll
      for (int jj = 0; jj < 8; ++jj)
        ax[jj] = *(const _Float16*)(XtB + xsw((quad*8 + jj)*8 + p, ms*16 + l15));
#pragma unroll
      for (int tj = 0; tj < 2; ++tj) {
        const f32x4 aU = MFMA(ax, bA[tj], zz);
        *(f16x4*)(YtB + xsw((tj*16 + l15)*8 + p, ms*16 + quad*4)) = cvt4z(aU);
      }
    }
  }
  __syncthreads();

  // ---- P6: out^T = U^T Wv'^T + b' + x : 32B/line stores (quad pairs) ----
  {
    const int oi = wv & 7, mg6 = wv >> 3;
    f32x4 acc[8] = {zz, zz, zz, zz, zz, zz, zz, zz};
#pragma unroll
    for (int kk = 0; kk < 4; ++kk) {
      const int co = kk*32 + quad*8;
#pragma unroll
      for (int mt = 0; mt < 8; ++mt) {
        const f16x8 av = *(const f16x8*)(YtB + xsw((mg6*8 + mt)*16 + l15, co));
        acc[mt] = MFMA(av, wp[kk], acc[mt]);
      }
    }
    const int o = oi*16 + l15;
    const float bb = bfp[128 + o];
    float* outp = out + pbase + (size_t)o*131072;
#pragma unroll
    for (int mt = 0; mt < 8; ++mt) {
      const int vox0 = (mg6*8 + mt)*16 + quad*4;   // voxel = d*8 + p
      const int d = vox0 >> 3;
      f32x4 v;
#pragma unroll
      for (int r = 0; r < 4; ++r)
        v[r] = acc[mt][r] + bb +
               (float)*(const _Float16*)(XtB + xsw(vox0 + r, o));
      *(f32x4*)(outp + (size_t)d*4096 + (vox0 & 7)) = v;
    }
  }
}

extern "C" void kernel_launch(void* const* d_in, const int* in_sizes, int n_in,
                              void* d_out, int out_size, void* d_ws, size_t ws_size,
                              hipStream_t stream) {
  const float* x  = (const float*)d_in[0];
  const float* Wk = (const float*)d_in[1];
  const float* bk = (const float*)d_in[2];
  const float* Wq = (const float*)d_in[3];
  const float* bq = (const float*)d_in[4];
  const float* Wv = (const float*)d_in[5];
  const float* bv = (const float*)d_in[6];
  const float* Wo = (const float*)d_in[7];
  const float* bo = (const float*)d_in[8];
  float* out = (float*)d_out;
  _Float16* wh = (_Float16*)d_ws;
  float* bf = (float*)((char*)d_ws + 65536);
  _Float16* Xg = (_Float16*)((char*)d_ws + 131072);  // needs 67.1 MB of ws

  prep_transpose_kernel<<<dim3(4160), dim3(256), 0, stream>>>(
      x, Xg, Wk, bk, Wq, bq, Wv, bv, Wo, bo, wh, bf);
  attn_kernel<<<dim3(1024), dim3(1024), 0, stream>>>(Xg, wh, bf, out);
}